// Round 5
// baseline (114.737 us; speedup 1.0000x reference)
//
#include <hip/hip_runtime.h>

#define L_AUDIO 15360000
#define PADLEN  15361024   // L + 1024
#define FRAMES  30001
#define CHP     513        // channel pairs (real k, imag k+513)
#define NBAS    (1026*1024)

#define BM  256            // frames per block
#define BNP 128            // channel pairs per block (256 basis rows)
#define BK  64
#define NKT 16             // 1024 / BK
#define NCB 5              // ceil(513/128)
#define NFB 118            // ceil(30001/256)
#define NWG (NFB*NCB)      // 590

typedef __attribute__((ext_vector_type(8))) short short8;
typedef __attribute__((ext_vector_type(4))) float f32x4;

__device__ __forceinline__ unsigned short f2bf(float f) {
    unsigned int u = __float_as_uint(f);
    u += 0x7fffu + ((u >> 16) & 1u);   // round-to-nearest-even
    return (unsigned short)(u >> 16);
}

__global__ __launch_bounds__(256) void prep_pad_k(const float* __restrict__ a,
                                                  unsigned short* __restrict__ pad) {
    long i = (long)blockIdx.x * blockDim.x + threadIdx.x;   // [0, PADLEN/4)
    long p0 = i * 4;
    if (p0 >= 512 && p0 + 4 <= 512 + L_AUDIO) {
        const float4 v = *reinterpret_cast<const float4*>(a + (p0 - 512));
        ushort4 o;
        o.x = f2bf(v.x); o.y = f2bf(v.y); o.z = f2bf(v.z); o.w = f2bf(v.w);
        *reinterpret_cast<ushort4*>(pad + p0) = o;
    } else {
        for (int j = 0; j < 4; ++j) {
            long p = p0 + j;
            long src = p - 512;
            if (p < 512) src = 512 - p;
            else if (src >= L_AUDIO) src = 2L*L_AUDIO - 2 - src;
            pad[p] = f2bf(a[src]);
        }
    }
}

__global__ __launch_bounds__(256) void prep_bas_k(const float* __restrict__ b,
                                                  unsigned short* __restrict__ o) {
    long i = (long)blockIdx.x * blockDim.x + threadIdx.x;
    const float4 v = *reinterpret_cast<const float4*>(b + i * 4);
    ushort4 u;
    u.x = f2bf(v.x); u.y = f2bf(v.y); u.z = f2bf(v.z); u.w = f2bf(v.w);
    *reinterpret_cast<ushort4*>(o + i * 4) = u;
}

// 256(frames) x 256(basis rows = 128 pairs) x K=64 tiles, 8 waves (2M x 4N),
// per-wave 128x64. B rows reordered in 16-row frags (real/imag interleaved)
// so the power epilogue stays wave-local. LDS XOR-swizzle per rule 21.
// Flat per-tile schedule: issue all 8 next-tile gload_lds at tile head,
// counted vmcnt(8) (T4), barrier, then 24 ds_read + 64 MFMA left to the
// compiler's lgkmcnt scheduling (LDS and MFMA pipes overlap), barrier.
__global__ __launch_bounds__(512, 2) void stft_gemm(const unsigned short* __restrict__ pad,
                                                    const unsigned short* __restrict__ bas,
                                                    float* __restrict__ out) {
    __shared__ unsigned short lsA[2][BM * BK];   // 2 x 32 KB
    __shared__ unsigned short lsB[2][BM * BK];   // 2 x 32 KB

    const int tid  = threadIdx.x;
    const int w    = tid >> 6;
    const int lane = tid & 63;
    const int l15  = lane & 15;
    const int lk   = lane >> 4;
    const int wm   = w >> 2;          // 0..1 (M half)
    const int wn   = w & 3;           // 0..3 (N quarter)

    // bijective XCD-chunked remap (m204): NWG=590 = 8*73+6
    const int orig = blockIdx.x;
    const int xcd  = orig & 7;
    const int lid  = orig >> 3;
    const int wg   = (xcd < 6 ? xcd * 74 : 6 * 74 + (xcd - 6) * 73) + lid;
    const int fb   = wg / NCB;
    const int cb   = wg - fb * NCB;
    const long t0  = (long)fb * BM;
    const int  c0  = cb * BNP;

    // Per-thread staging sources (chunk c = j*512 + tid of 2048 16B-chunks).
    const unsigned short* aS[4];
    const unsigned short* bS[4];
    #pragma unroll
    for (int j = 0; j < 4; ++j) {
        const int c   = j * 512 + tid;
        const int row = c >> 3;                  // 0..255
        const int sc  = (c & 7) ^ (row & 7);     // pre-swizzled source chunk
        long tf = t0 + row; if (tf > FRAMES - 1) tf = FRAMES - 1;
        aS[j] = pad + tf * 512 + sc * 8;
        const int g = row >> 4;                  // 16-row frag id
        int ch = c0 + (g >> 1) * 16 + (row & 15); if (ch > 512) ch = 512;
        const long brow = (g & 1) ? (long)(513 + ch) : (long)ch;
        bS[j] = bas + brow * 1024 + sc * 8;
    }

    f32x4 acc[8][4];
    #pragma unroll
    for (int a = 0; a < 8; ++a)
        #pragma unroll
        for (int b = 0; b < 4; ++b)
            acc[a][b] = (f32x4){0.f, 0.f, 0.f, 0.f};

    const int wmBase = wm * 128;
    const int wnBase = wn * 64;

#define GLD(dst, src) __builtin_amdgcn_global_load_lds( \
        (const __attribute__((address_space(1))) unsigned int*)(src), \
        (__attribute__((address_space(3))) unsigned int*)(dst), 16, 0, 0)

#define LDSREAD(basePtr, r, S) \
    (*reinterpret_cast<const short8*>(reinterpret_cast<const char*>(basePtr) \
        + (r) * 128 + ((((S) * 4 + lk) ^ ((r) & 7)) << 4)))

    // Prologue: stage tile 0 fully into buf 0.
    #pragma unroll
    for (int j = 0; j < 4; ++j) {
        GLD(&lsA[0][(j * 512 + tid) * 8], aS[j]);
        GLD(&lsB[0][(j * 512 + tid) * 8], bS[j]);
    }

    for (int t = 0; t < NKT; ++t) {
        unsigned short* curA = lsA[t & 1];
        unsigned short* curB = lsB[t & 1];
        unsigned short* nxtA = lsA[(t & 1) ^ 1];
        unsigned short* nxtB = lsB[(t & 1) ^ 1];
        const bool more = (t + 1 < NKT);
        const int ko = (t + 1) * BK;             // element offset of next tile

        if (more) {
            #pragma unroll
            for (int j = 0; j < 4; ++j) {
                GLD(&nxtA[(j * 512 + tid) * 8], aS[j] + ko);
                GLD(&nxtB[(j * 512 + tid) * 8], bS[j] + ko);
            }
            asm volatile("s_waitcnt vmcnt(8)" ::: "memory");  // tile t landed; t+1 in flight
        } else {
            asm volatile("s_waitcnt vmcnt(0)" ::: "memory");
        }
        __builtin_amdgcn_s_barrier();
        asm volatile("" ::: "memory");

        // Interleaved compute: compiler schedules ds_reads ahead of their
        // consuming MFMAs with fine-grained lgkmcnt (no intra-tile barriers).
        #pragma unroll
        for (int S = 0; S < 2; ++S) {
            short8 bf[4];
            #pragma unroll
            for (int b = 0; b < 4; ++b)
                bf[b] = LDSREAD(curB, wnBase + b * 16 + l15, S);
            #pragma unroll
            for (int mq = 0; mq < 8; ++mq) {
                short8 af = LDSREAD(curA, wmBase + mq * 16 + l15, S);
                #pragma unroll
                for (int b = 0; b < 4; ++b)
                    acc[mq][b] = __builtin_amdgcn_mfma_f32_16x16x32_bf16(
                        af, bf[b], acc[mq][b], 0, 0, 0);
            }
        }

        asm volatile("" ::: "memory");
        __builtin_amdgcn_s_barrier();                 // all reads of cur done
        asm volatile("" ::: "memory");
    }

    // Epilogue: out[ch][t] = re^2 + im^2
    // D layout: col = lane&15 (pair), row = lk*4 + reg (frame)
    const int tb = (int)t0 + wmBase;
    #pragma unroll
    for (int a = 0; a < 8; ++a) {
        #pragma unroll
        for (int q = 0; q < 2; ++q) {
            const int ch = c0 + wn * 32 + q * 16 + l15;
            if (ch >= CHP) continue;
            const long ob = (long)ch * FRAMES;
            const int tv = tb + a * 16 + lk * 4;
            const f32x4 re = acc[a][q * 2];
            const f32x4 im = acc[a][q * 2 + 1];
            if (tv + 3 < FRAMES) {
                #pragma unroll
                for (int r = 0; r < 4; ++r)
                    out[ob + tv + r] = re[r] * re[r] + im[r] * im[r];
            } else {
                #pragma unroll
                for (int r = 0; r < 4; ++r)
                    if (tv + r < FRAMES)
                        out[ob + tv + r] = re[r] * re[r] + im[r] * im[r];
            }
        }
    }
}

extern "C" void kernel_launch(void* const* d_in, const int* in_sizes, int n_in,
                              void* d_out, int out_size, void* d_ws, size_t ws_size,
                              hipStream_t stream) {
    const float* audio = (const float*)d_in[0];
    const float* basis = (const float*)d_in[1];
    float* out = (float*)d_out;

    unsigned short* pad = (unsigned short*)d_ws;
    unsigned short* bas = pad + PADLEN;

    prep_pad_k<<<PADLEN / 4 / 256, 256, 0, stream>>>(audio, pad);
    prep_bas_k<<<NBAS / 4 / 256, 256, 0, stream>>>(basis, bas);

    stft_gemm<<<NWG, 512, 0, stream>>>(pad, bas, out);
}